// Round 1
// baseline (252.674 us; speedup 1.0000x reference)
//
#include <hip/hip_runtime.h>

typedef __attribute__((ext_vector_type(8))) __bf16 bf16x8;
typedef __attribute__((ext_vector_type(4))) float f32x4;

__device__ __forceinline__ unsigned short f2bf(float f) {
  unsigned u = __builtin_bit_cast(unsigned, f);
  u = (u + 0x7FFFu + ((u >> 16) & 1u)) >> 16;
  return (unsigned short)u;
}
__device__ __forceinline__ float bf2f(unsigned short h) {
  return __builtin_bit_cast(float, (unsigned)h << 16);
}

// ---------------- sum of squares (for g/||w||) ----------------
__global__ __launch_bounds__(256) void k_sumsq(const float* __restrict__ w, int n4,
                                               float* __restrict__ out) {
  int tid = threadIdx.x;
  float s = 0.f;
  for (int i = blockIdx.x * 256 + tid; i < n4; i += gridDim.x * 256) {
    float4 v = ((const float4*)w)[i];
    s += v.x * v.x + v.y * v.y + v.z * v.z + v.w * v.w;
  }
  for (int off = 32; off; off >>= 1) s += __shfl_down(s, off);
  __shared__ float red[4];
  if ((tid & 63) == 0) red[tid >> 6] = s;
  __syncthreads();
  if (tid == 0) atomicAdd(out, red[0] + red[1] + red[2] + red[3]);
}

// ---------------- f32 -> bf16 convert ----------------
__global__ __launch_bounds__(256) void k_cvt(const float* __restrict__ in,
                                             unsigned short* __restrict__ out, int n8) {
  for (int i = blockIdx.x * 256 + threadIdx.x; i < n8; i += gridDim.x * 256) {
    float4 a = ((const float4*)in)[2 * i];
    float4 b = ((const float4*)in)[2 * i + 1];
    uint4 o;
    o.x = f2bf(a.x) | ((unsigned)f2bf(a.y) << 16);
    o.y = f2bf(a.z) | ((unsigned)f2bf(a.w) << 16);
    o.z = f2bf(b.x) | ((unsigned)f2bf(b.y) << 16);
    o.w = f2bf(b.z) | ((unsigned)f2bf(b.w) << 16);
    ((uint4*)out)[i] = o;
  }
}

// ---------------- bf16 GEMM: C = relu(s*(A @ B^T) + bias), bf16 out ----------------
// A [M][K] bf16 row-major, B [N][K] bf16 row-major. 128x128 tile, BK=64,
// 256 threads = 4 waves, each wave 64x64 (4x4 frags of mfma 16x16x32).
__global__ __launch_bounds__(256, 2) void k_gemm_bt(
    const unsigned short* __restrict__ A, const unsigned short* __restrict__ B,
    const float* __restrict__ bias, const float* __restrict__ gptr,
    const float* __restrict__ ssptr, unsigned short* __restrict__ C,
    int M, int N, int K, int nbn) {
  __shared__ __align__(16) unsigned short lA[128 * 64];
  __shared__ __align__(16) unsigned short lB[128 * 64];
  int tid = threadIdx.x;
  int wid = tid >> 6, lane = tid & 63;
  int l15 = lane & 15, l4 = lane >> 4;
  int w0 = wid >> 1, w1 = wid & 1;

  // bijective XCD swizzle (gridDim.x % 8 == 0)
  int nwg = gridDim.x;
  int wg = blockIdx.x;
  int cpx = nwg >> 3;
  wg = (wg & 7) * cpx + (wg >> 3);
  int bm = wg / nbn, bn = wg % nbn;

  const unsigned short* Ab = A + (size_t)bm * 128 * K;
  const unsigned short* Bb = B + (size_t)bn * 128 * K;

  f32x4 acc[4][4] = {};

  for (int k0 = 0; k0 < K; k0 += 64) {
    __syncthreads();
#pragma unroll
    for (int i = 0; i < 4; ++i) {
      int ebase = (i * 4 + wid) << 9;  // wave-uniform 512-elem segment
      int eoff = ebase + lane * 8;
      int row = eoff >> 6, col = eoff & 63;
      __builtin_amdgcn_global_load_lds(
          (const __attribute__((address_space(1))) unsigned int*)(Ab + (size_t)row * K + k0 + col),
          (__attribute__((address_space(3))) unsigned int*)(lA + ebase), 16, 0, 0);
      __builtin_amdgcn_global_load_lds(
          (const __attribute__((address_space(1))) unsigned int*)(Bb + (size_t)row * K + k0 + col),
          (__attribute__((address_space(3))) unsigned int*)(lB + ebase), 16, 0, 0);
    }
    __syncthreads();
#pragma unroll
    for (int ks = 0; ks < 2; ++ks) {
      bf16x8 af[4], bfr[4];
#pragma unroll
      for (int mi = 0; mi < 4; ++mi)
        af[mi] = *(const bf16x8*)(lA + ((w0 * 64 + mi * 16 + l15) * 64 + ks * 32 + l4 * 8));
#pragma unroll
      for (int nj = 0; nj < 4; ++nj)
        bfr[nj] = *(const bf16x8*)(lB + ((w1 * 64 + nj * 16 + l15) * 64 + ks * 32 + l4 * 8));
#pragma unroll
      for (int mi = 0; mi < 4; ++mi)
#pragma unroll
        for (int nj = 0; nj < 4; ++nj)
          acc[mi][nj] =
              __builtin_amdgcn_mfma_f32_16x16x32_bf16(af[mi], bfr[nj], acc[mi][nj], 0, 0, 0);
    }
  }

  float s = gptr[0] / sqrtf(ssptr[0]);
#pragma unroll
  for (int mi = 0; mi < 4; ++mi)
#pragma unroll
    for (int nj = 0; nj < 4; ++nj) {
      int col = bn * 128 + w1 * 64 + nj * 16 + l15;
      float bv = bias[col];
#pragma unroll
      for (int r = 0; r < 4; ++r) {
        int row = bm * 128 + w0 * 64 + mi * 16 + l4 * 4 + r;
        float v = fmaxf(acc[mi][nj][r] * s + bv, 0.f);
        C[(size_t)row * N + col] = f2bf(v);
      }
    }
}

// ---------------- glimpse: out[b,h,v,q] = sum_k hm[h,k]*v_[b,v,k]*q_[b,q,k] + hb[h] ----
// block = (h*64 + b): 512 blocks (same b -> same XCD), 256 thr = 4 waves,
// wave w computes v-rows [w*32, w*32+32) x all 32 q. K-loop BK=64 over 3072.
__global__ __launch_bounds__(256, 2) void k_glimpse(
    const unsigned short* __restrict__ Vh, const unsigned short* __restrict__ Qh,
    const float* __restrict__ hmat, const float* __restrict__ hbias,
    float* __restrict__ out) {
  __shared__ __align__(16) unsigned short lV[128 * 64];
  __shared__ __align__(16) unsigned short lQ[32 * 64];
  int tid = threadIdx.x;
  int wid = tid >> 6, lane = tid & 63;
  int l15 = lane & 15, l4 = lane >> 4;

  int id = blockIdx.x;
  int b = id & 63, h = id >> 6;

  const unsigned short* Vb = Vh + (size_t)b * 128 * 3072;
  const unsigned short* Qb = Qh + (size_t)b * 32 * 3072;
  const float* hrow = hmat + h * 3072;

  f32x4 acc[2][2] = {};

  int eoff = tid * 8;          // q-tile staging: 32*64 = 2048 elems = 256 thr * 8
  int qr = eoff >> 6, qc = eoff & 63;

  for (int k0 = 0; k0 < 3072; k0 += 64) {
    __syncthreads();
#pragma unroll
    for (int i = 0; i < 4; ++i) {
      int ebase = (i * 4 + wid) << 9;
      int eo = ebase + lane * 8;
      int row = eo >> 6, col = eo & 63;
      __builtin_amdgcn_global_load_lds(
          (const __attribute__((address_space(1))) unsigned int*)(Vb + (size_t)row * 3072 + k0 + col),
          (__attribute__((address_space(3))) unsigned int*)(lV + ebase), 16, 0, 0);
    }
    {
      uint4 qv = *(const uint4*)(Qb + (size_t)qr * 3072 + k0 + qc);
      const float* hp = hrow + k0 + qc;
      float4 h0 = ((const float4*)hp)[0];
      float4 h1 = ((const float4*)hp)[1];
      uint4 o;
      o.x = f2bf(bf2f((unsigned short)(qv.x & 0xffff)) * h0.x) |
            ((unsigned)f2bf(bf2f((unsigned short)(qv.x >> 16)) * h0.y) << 16);
      o.y = f2bf(bf2f((unsigned short)(qv.y & 0xffff)) * h0.z) |
            ((unsigned)f2bf(bf2f((unsigned short)(qv.y >> 16)) * h0.w) << 16);
      o.z = f2bf(bf2f((unsigned short)(qv.z & 0xffff)) * h1.x) |
            ((unsigned)f2bf(bf2f((unsigned short)(qv.z >> 16)) * h1.y) << 16);
      o.w = f2bf(bf2f((unsigned short)(qv.w & 0xffff)) * h1.z) |
            ((unsigned)f2bf(bf2f((unsigned short)(qv.w >> 16)) * h1.w) << 16);
      *(uint4*)(lQ + eoff) = o;
    }
    __syncthreads();
#pragma unroll
    for (int ks = 0; ks < 2; ++ks) {
      bf16x8 af[2], bfr[2];
#pragma unroll
      for (int mi = 0; mi < 2; ++mi)
        af[mi] = *(const bf16x8*)(lV + ((wid * 32 + mi * 16 + l15) * 64 + ks * 32 + l4 * 8));
#pragma unroll
      for (int nj = 0; nj < 2; ++nj)
        bfr[nj] = *(const bf16x8*)(lQ + ((nj * 16 + l15) * 64 + ks * 32 + l4 * 8));
#pragma unroll
      for (int mi = 0; mi < 2; ++mi)
#pragma unroll
        for (int nj = 0; nj < 2; ++nj)
          acc[mi][nj] =
              __builtin_amdgcn_mfma_f32_16x16x32_bf16(af[mi], bfr[nj], acc[mi][nj], 0, 0, 0);
    }
  }

  float hb = hbias[h];
  float* ob = out + (size_t)(b * 8 + h) * 128 * 32;
#pragma unroll
  for (int mi = 0; mi < 2; ++mi)
#pragma unroll
    for (int nj = 0; nj < 2; ++nj)
#pragma unroll
      for (int r = 0; r < 4; ++r) {
        int row = wid * 32 + mi * 16 + l4 * 4 + r;
        int col = nj * 16 + l15;
        ob[row * 32 + col] = acc[mi][nj][r] + hb;
      }
}

extern "C" void kernel_launch(void* const* d_in, const int* in_sizes, int n_in,
                              void* d_out, int out_size, void* d_ws, size_t ws_size,
                              hipStream_t stream) {
  const float* v = (const float*)d_in[0];
  const float* q = (const float*)d_in[1];
  const float* v_w = (const float*)d_in[2];
  const float* v_g = (const float*)d_in[3];
  const float* v_b = (const float*)d_in[4];
  const float* q_w = (const float*)d_in[5];
  const float* q_g = (const float*)d_in[6];
  const float* q_b = (const float*)d_in[7];
  const float* hmat = (const float*)d_in[8];
  const float* hbias = (const float*)d_in[9];
  float* out = (float*)d_out;

  // element counts
  const size_t n_v = 16777216;   // 64*128*2048
  const size_t n_vw = 6291456;   // 3072*2048
  const size_t n_q = 2097152;    // 64*32*1024
  const size_t n_qw = 3145728;   // 3072*1024
  const size_t n_vh = 25165824;  // 8192*3072
  const size_t n_qh = 6291456;   // 2048*3072

  char* ws = (char*)d_ws;
  float* ss = (float*)ws;
  size_t off = 256;
  unsigned short* v_bf = (unsigned short*)(ws + off);  off += n_v * 2;
  unsigned short* vw_bf = (unsigned short*)(ws + off); off += n_vw * 2;
  unsigned short* q_bf = (unsigned short*)(ws + off);  off += n_q * 2;
  unsigned short* qw_bf = (unsigned short*)(ws + off); off += n_qw * 2;
  unsigned short* v_h = (unsigned short*)(ws + off);   off += n_vh * 2;
  unsigned short* q_h = (unsigned short*)(ws + off);   off += n_qh * 2;

  (void)hipMemsetAsync(ss, 0, 8, stream);
  k_sumsq<<<512, 256, 0, stream>>>(v_w, (int)(n_vw / 4), ss + 0);
  k_sumsq<<<512, 256, 0, stream>>>(q_w, (int)(n_qw / 4), ss + 1);

  k_cvt<<<1024, 256, 0, stream>>>(v, v_bf, (int)(n_v / 8));
  k_cvt<<<1024, 256, 0, stream>>>(v_w, vw_bf, (int)(n_vw / 8));
  k_cvt<<<1024, 256, 0, stream>>>(q, q_bf, (int)(n_q / 8));
  k_cvt<<<1024, 256, 0, stream>>>(q_w, qw_bf, (int)(n_qw / 8));

  k_gemm_bt<<<64 * 24, 256, 0, stream>>>(v_bf, vw_bf, v_b, v_g, ss + 0, v_h,
                                         8192, 3072, 2048, 24);
  k_gemm_bt<<<16 * 24, 256, 0, stream>>>(q_bf, qw_bf, q_b, q_g, ss + 1, q_h,
                                         2048, 3072, 1024, 24);

  k_glimpse<<<512, 256, 0, stream>>>(v_h, q_h, hmat, hbias, out);
}

// Round 2
// 246.247 us; speedup vs baseline: 1.0261x; 1.0261x over previous
//
#include <hip/hip_runtime.h>

typedef __attribute__((ext_vector_type(8))) __bf16 bf16x8;
typedef __attribute__((ext_vector_type(4))) float f32x4;

__device__ __forceinline__ unsigned short f2bf(float f) {
  unsigned u = __builtin_bit_cast(unsigned, f);
  u = (u + 0x7FFFu + ((u >> 16) & 1u)) >> 16;
  return (unsigned short)u;
}
__device__ __forceinline__ float bf2f(unsigned short h) {
  return __builtin_bit_cast(float, (unsigned)h << 16);
}

// ---------------- sum of squares (for g/||w||) ----------------
__global__ __launch_bounds__(256) void k_sumsq(const float* __restrict__ w, int n4,
                                               float* __restrict__ out) {
  int tid = threadIdx.x;
  float s = 0.f;
  for (int i = blockIdx.x * 256 + tid; i < n4; i += gridDim.x * 256) {
    float4 v = ((const float4*)w)[i];
    s += v.x * v.x + v.y * v.y + v.z * v.z + v.w * v.w;
  }
  for (int off = 32; off; off >>= 1) s += __shfl_down(s, off);
  __shared__ float red[4];
  if ((tid & 63) == 0) red[tid >> 6] = s;
  __syncthreads();
  if (tid == 0) atomicAdd(out, red[0] + red[1] + red[2] + red[3]);
}

// ---------------- f32 -> bf16 convert ----------------
__global__ __launch_bounds__(256) void k_cvt(const float* __restrict__ in,
                                             unsigned short* __restrict__ out, int n8) {
  for (int i = blockIdx.x * 256 + threadIdx.x; i < n8; i += gridDim.x * 256) {
    float4 a = ((const float4*)in)[2 * i];
    float4 b = ((const float4*)in)[2 * i + 1];
    uint4 o;
    o.x = f2bf(a.x) | ((unsigned)f2bf(a.y) << 16);
    o.y = f2bf(a.z) | ((unsigned)f2bf(a.w) << 16);
    o.z = f2bf(b.x) | ((unsigned)f2bf(b.y) << 16);
    o.w = f2bf(b.z) | ((unsigned)f2bf(b.w) << 16);
    ((uint4*)out)[i] = o;
  }
}

// ======== 256x256 8-wave 4-phase pipelined GEMM: C = relu(s*(A@B^T)+bias), bf16 out ====
// A [M][K], B [N][K] bf16 row-major. BK=64, 512 thr = 8 waves (2Mx4N),
// wave tile 128x64 = acc[8][4] of 16x16 frags. LDS 128 KiB (A,B double-buffered).
// Swizzle: LDS chunk ^= (row&7) applied via pre-swizzled GLOBAL source (linear DMA dest)
// and matching XOR on ds_read addresses (rule 21).
// Pipeline (per K-tile t, phases P1..P4):
//   P1: read A(mq0)+B(nq0) frags; stage (t+1,A-hi); bar; lgkm0; MFMA q(0,0); vmcnt(6); bar
//   P2: read B(nq1);             stage (t+1,B-hi); bar; lgkm0; MFMA q(0,1);            bar
//   P3: read A(mq1);             stage (t+2,A-lo); bar; lgkm0; MFMA q(1,0);            bar
//   P4:                          stage (t+2,B-lo); bar; lgkm0; MFMA q(1,1); vmcnt(8); bar
// Retirement: A-lo/B-lo only read in P1 -> (t+2) halves may land in CURRENT buffer
// after P1's end barrier. vmcnt(8) @P4 completes (t+1,Alo/Blo); vmcnt(6) @P1 completes
// (t,Bhi)/(t,Ahi). Tail pads (clamped source tile) so vmcnt counts stay exact.
__global__ __launch_bounds__(512, 2) void k_gemm256(
    const unsigned short* __restrict__ A, const unsigned short* __restrict__ B,
    const float* __restrict__ bias, const float* __restrict__ gptr,
    const float* __restrict__ ssptr, unsigned short* __restrict__ C,
    int M, int N, int K, int nbn) {
  __shared__ __align__(16) unsigned short lA[2 * 16384];
  __shared__ __align__(16) unsigned short lB[2 * 16384];
  const int tid = threadIdx.x;
  const int wid = tid >> 6, lane = tid & 63;
  const int l15 = lane & 15, l4 = lane >> 4;
  const int wm = wid >> 2, wn = wid & 3;  // 2 x 4 waves

  // bijective XCD swizzle (gridDim.x % 8 == 0)
  int nwg = gridDim.x;
  int wg = (blockIdx.x & 7) * (nwg >> 3) + (blockIdx.x >> 3);
  int bm = wg / nbn, bn = wg % nbn;

  const unsigned short* Ab = A + (size_t)bm * 256 * K;
  const unsigned short* Bb = B + (size_t)bn * 256 * K;

  // staging source element offsets for (j, half): row*K + swizzled col
  int soff[2][2];
  {
    int base = wid * 512 + lane * 8;
#pragma unroll
    for (int j = 0; j < 2; ++j) {
      int eoff = base + j * 4096;
      int row = eoff >> 6;
      int chunk = (eoff >> 3) & 7;
      int scol = (chunk ^ (row & 7)) << 3;
#pragma unroll
      for (int h = 0; h < 2; ++h) soff[j][h] = (h * 128 + row) * K + scol;
    }
  }

#define STAGE(XLDS, XG, BUFI, HALF, UT)                                                   \
  {                                                                                       \
    const unsigned short* gsrc = (XG) + (size_t)(UT)*64;                                  \
    _Pragma("unroll") for (int j = 0; j < 2; ++j) {                                       \
      __builtin_amdgcn_global_load_lds(                                                   \
          (const __attribute__((address_space(1))) unsigned int*)(gsrc + soff[j][HALF]),  \
          (__attribute__((address_space(3))) unsigned int*)((XLDS) + (BUFI)*16384 +       \
                                                            (HALF)*8192 + wid * 512 +     \
                                                            j * 4096),                    \
          16, 0, 0);                                                                      \
    }                                                                                     \
  }

#define LDA(MQ, BUFE)                                                                  \
  _Pragma("unroll") for (int mi2 = 0; mi2 < 4; ++mi2) {                                \
    int rl = (MQ)*128 + wm * 64 + mi2 * 16 + l15;                                      \
    int sw8 = rl & 7;                                                                  \
    a_[mi2][0] = *(const bf16x8*)(lA + (BUFE) + rl * 64 + ((l4 ^ sw8) << 3));          \
    a_[mi2][1] = *(const bf16x8*)(lA + (BUFE) + rl * 64 + (((4 | l4) ^ sw8) << 3));    \
  }

#define LDB(NQ, BUFE)                                                                  \
  _Pragma("unroll") for (int nj2 = 0; nj2 < 2; ++nj2) {                                \
    int rl = (NQ)*128 + wn * 32 + nj2 * 16 + l15;                                      \
    int sw8 = rl & 7;                                                                  \
    b_[(NQ)*2 + nj2][0] =                                                              \
        *(const bf16x8*)(lB + (BUFE) + rl * 64 + ((l4 ^ sw8) << 3));                   \
    b_[(NQ)*2 + nj2][1] =                                                              \
        *(const bf16x8*)(lB + (BUFE) + rl * 64 + (((4 | l4) ^ sw8) << 3));             \
  }

#define MFMA16(MQ, NQ)                                                                 \
  _Pragma("unroll") for (int ks = 0; ks < 2; ++ks)                                     \
      _Pragma("unroll") for (int mi2 = 0; mi2 < 4; ++mi2)                              \
          _Pragma("unroll") for (int nj2 = 0; nj2 < 2; ++nj2)                          \
              acc[(MQ)*4 + mi2][(NQ)*2 + nj2] = __builtin_amdgcn_mfma_f32_16x16x32_bf16( \
                  a_[mi2][ks], b_[(NQ)*2 + nj2][ks], acc[(MQ)*4 + mi2][(NQ)*2 + nj2],  \
                  0, 0, 0);

#define WAIT_LGKM0()                                   \
  asm volatile("s_waitcnt lgkmcnt(0)" ::: "memory");   \
  __builtin_amdgcn_sched_barrier(0);

  f32x4 acc[8][4] = {};
  bf16x8 a_[4][2], b_[4][2];

  const int nt = K >> 6;
  const int t1p = (nt > 1) ? 1 : 0;

  // ---- prologue: issue (0,Alo)(0,Blo) | (0,Ahi)(0,Bhi)(1,Alo)(1,Blo), wait oldest 4 ----
  STAGE(lA, Ab, 0, 0, 0)
  STAGE(lB, Bb, 0, 0, 0)
  __builtin_amdgcn_sched_barrier(0);
  STAGE(lA, Ab, 0, 1, 0)
  STAGE(lB, Bb, 0, 1, 0)
  STAGE(lA, Ab, 1, 0, t1p)
  STAGE(lB, Bb, 1, 0, t1p)
  asm volatile("s_waitcnt vmcnt(8)" ::: "memory");
  __builtin_amdgcn_sched_barrier(0);
  __builtin_amdgcn_s_barrier();

  for (int t = 0; t < nt; ++t) {
    const int bufe = (t & 1) << 14;
    const int nbi = (t + 1) & 1;
    const int cbi = t & 1;
    const int u1 = (t + 1 < nt) ? t + 1 : nt - 1;
    const int u2 = (t + 2 < nt) ? t + 2 : nt - 1;

    // ---- P1 ----
    LDA(0, bufe)
    LDB(0, bufe)
    STAGE(lA, Ab, nbi, 1, u1)
    __builtin_amdgcn_sched_barrier(0);
    __builtin_amdgcn_s_barrier();
    WAIT_LGKM0()
    __builtin_amdgcn_s_setprio(1);
    MFMA16(0, 0)
    __builtin_amdgcn_s_setprio(0);
    asm volatile("s_waitcnt vmcnt(6)" ::: "memory");
    __builtin_amdgcn_sched_barrier(0);
    __builtin_amdgcn_s_barrier();

    // ---- P2 ----
    LDB(1, bufe)
    STAGE(lB, Bb, nbi, 1, u1)
    __builtin_amdgcn_sched_barrier(0);
    __builtin_amdgcn_s_barrier();
    WAIT_LGKM0()
    __builtin_amdgcn_s_setprio(1);
    MFMA16(0, 1)
    __builtin_amdgcn_s_setprio(0);
    __builtin_amdgcn_s_barrier();

    // ---- P3 ----
    LDA(1, bufe)
    STAGE(lA, Ab, cbi, 0, u2)
    __builtin_amdgcn_sched_barrier(0);
    __builtin_amdgcn_s_barrier();
    WAIT_LGKM0()
    __builtin_amdgcn_s_setprio(1);
    MFMA16(1, 0)
    __builtin_amdgcn_s_setprio(0);
    __builtin_amdgcn_s_barrier();

    // ---- P4 ----
    STAGE(lB, Bb, cbi, 0, u2)
    __builtin_amdgcn_sched_barrier(0);
    __builtin_amdgcn_s_barrier();
    WAIT_LGKM0()
    __builtin_amdgcn_s_setprio(1);
    MFMA16(1, 1)
    __builtin_amdgcn_s_setprio(0);
    asm volatile("s_waitcnt vmcnt(8)" ::: "memory");
    __builtin_amdgcn_sched_barrier(0);
    __builtin_amdgcn_s_barrier();
  }

  // ---- epilogue ----
  float s = gptr[0] / sqrtf(ssptr[0]);
#pragma unroll
  for (int nj = 0; nj < 4; ++nj) {
    int gcol = bn * 256 + (nj >> 1) * 128 + wn * 32 + (nj & 1) * 16 + l15;
    float bv = bias[gcol];
#pragma unroll
    for (int mi = 0; mi < 8; ++mi) {
#pragma unroll
      for (int r = 0; r < 4; ++r) {
        int grow = bm * 256 + (mi >> 2) * 128 + wm * 64 + (mi & 3) * 16 + l4 * 4 + r;
        float v = fmaxf(acc[mi][nj][r] * s + bv, 0.f);
        C[(size_t)grow * N + gcol] = f2bf(v);
      }
    }
  }
#undef STAGE
#undef LDA
#undef LDB
#undef MFMA16
#undef WAIT_LGKM0
}

// ---------------- bf16 GEMM (m97 structure) for the small GEMM ----------------
__global__ __launch_bounds__(256, 2) void k_gemm_bt(
    const unsigned short* __restrict__ A, const unsigned short* __restrict__ B,
    const float* __restrict__ bias, const float* __restrict__ gptr,
    const float* __restrict__ ssptr, unsigned short* __restrict__ C,
    int M, int N, int K, int nbn) {
  __shared__ __align__(16) unsigned short lA[128 * 64];
  __shared__ __align__(16) unsigned short lB[128 * 64];
  int tid = threadIdx.x;
  int wid = tid >> 6, lane = tid & 63;
  int l15 = lane & 15, l4 = lane >> 4;
  int w0 = wid >> 1, w1 = wid & 1;

  int nwg = gridDim.x;
  int wg = blockIdx.x;
  int cpx = nwg >> 3;
  wg = (wg & 7) * cpx + (wg >> 3);
  int bm = wg / nbn, bn = wg % nbn;

  const unsigned short* Ab = A + (size_t)bm * 128 * K;
  const unsigned short* Bb = B + (size_t)bn * 128 * K;

  f32x4 acc[4][4] = {};

  for (int k0 = 0; k0 < K; k0 += 64) {
    __syncthreads();
#pragma unroll
    for (int i = 0; i < 4; ++i) {
      int ebase = (i * 4 + wid) << 9;
      int eoff = ebase + lane * 8;
      int row = eoff >> 6, col = eoff & 63;
      __builtin_amdgcn_global_load_lds(
          (const __attribute__((address_space(1))) unsigned int*)(Ab + (size_t)row * K + k0 + col),
          (__attribute__((address_space(3))) unsigned int*)(lA + ebase), 16, 0, 0);
      __builtin_amdgcn_global_load_lds(
          (const __attribute__((address_space(1))) unsigned int*)(Bb + (size_t)row * K + k0 + col),
          (__attribute__((address_space(3))) unsigned int*)(lB + ebase), 16, 0, 0);
    }
    __syncthreads();
#pragma unroll
    for (int ks = 0; ks < 2; ++ks) {
      bf16x8 af[4], bfr[4];
#pragma unroll
      for (int mi = 0; mi < 4; ++mi)
        af[mi] = *(const bf16x8*)(lA + ((w0 * 64 + mi * 16 + l15) * 64 + ks * 32 + l4 * 8));
#pragma unroll
      for (int nj = 0; nj < 4; ++nj)
        bfr[nj] = *(const bf16x8*)(lB + ((w1 * 64 + nj * 16 + l15) * 64 + ks * 32 + l4 * 8));
#pragma unroll
      for (int mi = 0; mi < 4; ++mi)
#pragma unroll
        for (int nj = 0; nj < 4; ++nj)
          acc[mi][nj] =
              __builtin_amdgcn_mfma_f32_16x16x32_bf16(af[mi], bfr[nj], acc[mi][nj], 0, 0, 0);
    }
  }

  float s = gptr[0] / sqrtf(ssptr[0]);
#pragma unroll
  for (int mi = 0; mi < 4; ++mi)
#pragma unroll
    for (int nj = 0; nj < 4; ++nj) {
      int col = bn * 128 + w1 * 64 + nj * 16 + l15;
      float bv = bias[col];
#pragma unroll
      for (int r = 0; r < 4; ++r) {
        int row = bm * 128 + w0 * 64 + mi * 16 + l4 * 4 + r;
        float v = fmaxf(acc[mi][nj][r] * s + bv, 0.f);
        C[(size_t)row * N + col] = f2bf(v);
      }
    }
}

// ---------------- glimpse: out[b,h,v,q] = sum_k hm[h,k]*v_[b,v,k]*q_[b,q,k] + hb[h] ----
__global__ __launch_bounds__(256, 2) void k_glimpse(
    const unsigned short* __restrict__ Vh, const unsigned short* __restrict__ Qh,
    const float* __restrict__ hmat, const float* __restrict__ hbias,
    float* __restrict__ out) {
  __shared__ __align__(16) unsigned short lV[128 * 64];
  __shared__ __align__(16) unsigned short lQ[32 * 64];
  int tid = threadIdx.x;
  int wid = tid >> 6, lane = tid & 63;
  int l15 = lane & 15, l4 = lane >> 4;

  int id = blockIdx.x;
  int b = id & 63, h = id >> 6;

  const unsigned short* Vb = Vh + (size_t)b * 128 * 3072;
  const unsigned short* Qb = Qh + (size_t)b * 32 * 3072;
  const float* hrow = hmat + h * 3072;

  f32x4 acc[2][2] = {};

  int eoff = tid * 8;
  int qr = eoff >> 6, qc = eoff & 63;

  for (int k0 = 0; k0 < 3072; k0 += 64) {
    __syncthreads();
#pragma unroll
    for (int i = 0; i < 4; ++i) {
      int ebase = (i * 4 + wid) << 9;
      int eo = ebase + lane * 8;
      int row = eo >> 6, col = eo & 63;
      __builtin_amdgcn_global_load_lds(
          (const __attribute__((address_space(1))) unsigned int*)(Vb + (size_t)row * 3072 + k0 + col),
          (__attribute__((address_space(3))) unsigned int*)(lV + ebase), 16, 0, 0);
    }
    {
      uint4 qv = *(const uint4*)(Qb + (size_t)qr * 3072 + k0 + qc);
      const float* hp = hrow + k0 + qc;
      float4 h0 = ((const float4*)hp)[0];
      float4 h1 = ((const float4*)hp)[1];
      uint4 o;
      o.x = f2bf(bf2f((unsigned short)(qv.x & 0xffff)) * h0.x) |
            ((unsigned)f2bf(bf2f((unsigned short)(qv.x >> 16)) * h0.y) << 16);
      o.y = f2bf(bf2f((unsigned short)(qv.y & 0xffff)) * h0.z) |
            ((unsigned)f2bf(bf2f((unsigned short)(qv.y >> 16)) * h0.w) << 16);
      o.z = f2bf(bf2f((unsigned short)(qv.z & 0xffff)) * h1.x) |
            ((unsigned)f2bf(bf2f((unsigned short)(qv.z >> 16)) * h1.y) << 16);
      o.w = f2bf(bf2f((unsigned short)(qv.w & 0xffff)) * h1.z) |
            ((unsigned)f2bf(bf2f((unsigned short)(qv.w >> 16)) * h1.w) << 16);
      *(uint4*)(lQ + eoff) = o;
    }
    __syncthreads();
#pragma unroll
    for (int ks = 0; ks < 2; ++ks) {
      bf16x8 af[2], bfr[2];
#pragma unroll
      for (int mi = 0; mi < 2; ++mi)
        af[mi] = *(const bf16x8*)(lV + ((wid * 32 + mi * 16 + l15) * 64 + ks * 32 + l4 * 8));
#pragma unroll
      for (int nj = 0; nj < 2; ++nj)
        bfr[nj] = *(const bf16x8*)(lQ + ((nj * 16 + l15) * 64 + ks * 32 + l4 * 8));
#pragma unroll
      for (int mi = 0; mi < 2; ++mi)
#pragma unroll
        for (int nj = 0; nj < 2; ++nj)
          acc[mi][nj] =
              __builtin_amdgcn_mfma_f32_16x16x32_bf16(af[mi], bfr[nj], acc[mi][nj], 0, 0, 0);
    }
  }

  float hb = hbias[h];
  float* ob = out + (size_t)(b * 8 + h) * 128 * 32;
#pragma unroll
  for (int mi = 0; mi < 2; ++mi)
#pragma unroll
    for (int nj = 0; nj < 2; ++nj)
#pragma unroll
      for (int r = 0; r < 4; ++r) {
        int row = wid * 32 + mi * 16 + l4 * 4 + r;
        int col = nj * 16 + l15;
        ob[row * 32 + col] = acc[mi][nj][r] + hb;
      }
}

extern "C" void kernel_launch(void* const* d_in, const int* in_sizes, int n_in,
                              void* d_out, int out_size, void* d_ws, size_t ws_size,
                              hipStream_t stream) {
  const float* v = (const float*)d_in[0];
  const float* q = (const float*)d_in[1];
  const float* v_w = (const float*)d_in[2];
  const float* v_g = (const float*)d_in[3];
  const float* v_b = (const float*)d_in[4];
  const float* q_w = (const float*)d_in[5];
  const float* q_g = (const float*)d_in[6];
  const float* q_b = (const float*)d_in[7];
  const float* hmat = (const float*)d_in[8];
  const float* hbias = (const float*)d_in[9];
  float* out = (float*)d_out;

  const size_t n_v = 16777216;   // 64*128*2048
  const size_t n_vw = 6291456;   // 3072*2048
  const size_t n_q = 2097152;    // 64*32*1024
  const size_t n_qw = 3145728;   // 3072*1024
  const size_t n_vh = 25165824;  // 8192*3072
  const size_t n_qh = 6291456;   // 2048*3072

  char* ws = (char*)d_ws;
  float* ss = (float*)ws;
  size_t off = 256;
  unsigned short* v_bf = (unsigned short*)(ws + off);  off += n_v * 2;
  unsigned short* vw_bf = (unsigned short*)(ws + off); off += n_vw * 2;
  unsigned short* q_bf = (unsigned short*)(ws + off);  off += n_q * 2;
  unsigned short* qw_bf = (unsigned short*)(ws + off); off += n_qw * 2;
  unsigned short* v_h = (unsigned short*)(ws + off);   off += n_vh * 2;
  unsigned short* q_h = (unsigned short*)(ws + off);   off += n_qh * 2;

  (void)hipMemsetAsync(ss, 0, 8, stream);
  k_sumsq<<<512, 256, 0, stream>>>(v_w, (int)(n_vw / 4), ss + 0);
  k_sumsq<<<512, 256, 0, stream>>>(q_w, (int)(n_qw / 4), ss + 1);

  k_cvt<<<1024, 256, 0, stream>>>(v, v_bf, (int)(n_v / 8));
  k_cvt<<<1024, 256, 0, stream>>>(v_w, vw_bf, (int)(n_vw / 8));
  k_cvt<<<1024, 256, 0, stream>>>(q, q_bf, (int)(n_q / 8));
  k_cvt<<<1024, 256, 0, stream>>>(q_w, qw_bf, (int)(n_qw / 8));

  // GEMM1: 8192x3072x2048, 256^2 tiles -> 32x12 = 384 blocks (%8==0)
  k_gemm256<<<384, 512, 0, stream>>>(v_bf, vw_bf, v_b, v_g, ss + 0, v_h,
                                     8192, 3072, 2048, 12);
  // GEMM2: 2048x3072x1024, 128^2 tiles -> 16x24 = 384 blocks
  k_gemm_bt<<<384, 256, 0, stream>>>(q_bf, qw_bf, q_b, q_g, ss + 1, q_h,
                                     2048, 3072, 1024, 24);

  k_glimpse<<<512, 256, 0, stream>>>(v_h, q_h, hmat, hbias, out);
}

// Round 3
// 237.560 us; speedup vs baseline: 1.0636x; 1.0366x over previous
//
#include <hip/hip_runtime.h>

typedef __attribute__((ext_vector_type(8))) __bf16 bf16x8;
typedef __attribute__((ext_vector_type(4))) float f32x4;
typedef const __attribute__((address_space(1))) unsigned int gas_u32;
typedef __attribute__((address_space(3))) unsigned int las_u32;

__device__ __forceinline__ unsigned short f2bf(float f) {
  unsigned u = __builtin_bit_cast(unsigned, f);
  u = (u + 0x7FFFu + ((u >> 16) & 1u)) >> 16;
  return (unsigned short)u;
}
__device__ __forceinline__ float bf2f(unsigned short h) {
  return __builtin_bit_cast(float, (unsigned)h << 16);
}

// ---------------- sum of squares (for g/||w||) ----------------
__global__ __launch_bounds__(256) void k_sumsq(const float* __restrict__ w, int n4,
                                               float* __restrict__ out) {
  int tid = threadIdx.x;
  float s = 0.f;
  for (int i = blockIdx.x * 256 + tid; i < n4; i += gridDim.x * 256) {
    float4 v = ((const float4*)w)[i];
    s += v.x * v.x + v.y * v.y + v.z * v.z + v.w * v.w;
  }
  for (int off = 32; off; off >>= 1) s += __shfl_down(s, off);
  __shared__ float red[4];
  if ((tid & 63) == 0) red[tid >> 6] = s;
  __syncthreads();
  if (tid == 0) atomicAdd(out, red[0] + red[1] + red[2] + red[3]);
}

// ---------------- f32 -> bf16 convert ----------------
__global__ __launch_bounds__(256) void k_cvt(const float* __restrict__ in,
                                             unsigned short* __restrict__ out, int n8) {
  for (int i = blockIdx.x * 256 + threadIdx.x; i < n8; i += gridDim.x * 256) {
    float4 a = ((const float4*)in)[2 * i];
    float4 b = ((const float4*)in)[2 * i + 1];
    uint4 o;
    o.x = f2bf(a.x) | ((unsigned)f2bf(a.y) << 16);
    o.y = f2bf(a.z) | ((unsigned)f2bf(a.w) << 16);
    o.z = f2bf(b.x) | ((unsigned)f2bf(b.y) << 16);
    o.w = f2bf(b.z) | ((unsigned)f2bf(b.w) << 16);
    ((uint4*)out)[i] = o;
  }
}

// ======== GEMM1: 128x384 tile, 8 waves, read-ahead rotation, counted vmcnt ========
// A [M][K], B [N][K] bf16 row-major. BK=64, grid = (M/128)*(N/384) blocks (tail-free
// 512 = 2/CU for GEMM1). Wave tile 64x96 (2Mx4N wave grid): acc[4][6].
// Frag groups: A0/A1 (mq quadrants, 4 frags), B0/B1 (nq quadrants, 6 frags).
// Stage units: 8/tile of 8KB (u0,u1=A; u2..u7=B), 2 issued/phase, DMA flight 2-5 phases.
// Phase rotation (tile t): ph0: issue B1(t) reads + u45(t+1), MFMA q00(A0,B0)
//                          ph1: issue A1(t) reads + u67(t+1), MFMA q01(A0,B1)
//   ph2: lgkm0 (WAR: all buf[t&1] reads done) + vmcnt(6) (u01(t+1) landed) + barrier;
//        issue A0(t+1) reads + u01(t+2), MFMA q10(A1,B0)
//   ph3: vmcnt(2) (u2-7(t+1) landed) + barrier; issue B0(t+1) reads + u23(t+2),
//        MFMA q11(A1,B1)
// ds_reads are plain loads -> compiler emits precise counted lgkmcnt before use, so
// reads issued in phase p complete under phase p's MFMA and gate phase p+1's MFMA.
__global__ __launch_bounds__(512, 2) void k_gemm_wn(
    const unsigned short* __restrict__ A, const unsigned short* __restrict__ B,
    const float* __restrict__ bias, const float* __restrict__ gptr,
    const float* __restrict__ ssptr, unsigned short* __restrict__ C,
    int M, int N, int K, int nbn) {
  __shared__ __align__(16) unsigned short lA[2 * 128 * 64];
  __shared__ __align__(16) unsigned short lB[2 * 384 * 64];
  const int tid = threadIdx.x;
  const int wid = tid >> 6, lane = tid & 63;
  const int l15 = lane & 15, l4 = lane >> 4;
  const int wm = wid >> 2, wn = wid & 3;  // 2M x 4N waves
  const int rr = tid >> 3;
  const int scol = ((tid & 7) ^ (rr & 7)) << 3;  // pre-swizzled source col (rule 21)

  // bijective XCD swizzle (gridDim.x % 8 == 0)
  int nwg = gridDim.x;
  int wg = (blockIdx.x & 7) * (nwg >> 3) + (blockIdx.x >> 3);
  int bm = wg / nbn, bn = wg % nbn;

  const unsigned short* Ab = A + (size_t)bm * 128 * K;
  const unsigned short* Bb = B + (size_t)bn * 384 * K;
  const int nt = K >> 6;

#define STAGEU(U, TS)                                                            \
  {                                                                              \
    int ts_ = (TS) < nt ? (TS) : nt - 1;                                         \
    if ((U) < 2) {                                                               \
      __builtin_amdgcn_global_load_lds(                                          \
          (gas_u32*)(Ab + (size_t)((U)*64 + rr) * K + ts_ * 64 + scol),          \
          (las_u32*)(lA + ((TS)&1) * 8192 + (U)*4096 + tid * 8), 16, 0, 0);      \
    } else {                                                                     \
      __builtin_amdgcn_global_load_lds(                                          \
          (gas_u32*)(Bb + (size_t)(((U)-2) * 64 + rr) * K + ts_ * 64 + scol),    \
          (las_u32*)(lB + ((TS)&1) * 24576 + ((U)-2) * 4096 + tid * 8), 16, 0,   \
          0);                                                                    \
    }                                                                            \
  }

#define LDSA(DST, MQ, TP)                                                        \
  _Pragma("unroll") for (int i2 = 0; i2 < 2; ++i2) {                             \
    int rl = wm * 64 + ((MQ)*2 + i2) * 16 + l15;                                 \
    const unsigned short* ap = lA + (TP)*8192 + rl * 64;                         \
    int s8 = rl & 7;                                                             \
    DST[i2][0] = *(const bf16x8*)(ap + ((l4 ^ s8) << 3));                        \
    DST[i2][1] = *(const bf16x8*)(ap + (((4 | l4) ^ s8) << 3));                  \
  }

#define LDSB(DST, NQ, TP)                                                        \
  _Pragma("unroll") for (int j3 = 0; j3 < 3; ++j3) {                             \
    int rl = wn * 96 + ((NQ)*3 + j3) * 16 + l15;                                 \
    const unsigned short* bp = lB + (TP)*24576 + rl * 64;                        \
    int s8 = rl & 7;                                                             \
    DST[j3][0] = *(const bf16x8*)(bp + ((l4 ^ s8) << 3));                        \
    DST[j3][1] = *(const bf16x8*)(bp + (((4 | l4) ^ s8) << 3));                  \
  }

#define MFMA12(MQ, NQ, AF, BF)                                                   \
  _Pragma("unroll") for (int ks = 0; ks < 2; ++ks)                               \
  _Pragma("unroll") for (int i2 = 0; i2 < 2; ++i2)                               \
  _Pragma("unroll") for (int j3 = 0; j3 < 3; ++j3)                               \
    acc[(MQ)*2 + i2][(NQ)*3 + j3] = __builtin_amdgcn_mfma_f32_16x16x32_bf16(     \
        AF[i2][ks], BF[j3][ks], acc[(MQ)*2 + i2][(NQ)*3 + j3], 0, 0, 0);

  f32x4 acc[4][6] = {};
  bf16x8 a0_[2][2], a1_[2][2], b0_[3][2], b1_[3][2];

  // ---- prologue: tile0 u0-7 + tile1 u01 in flight; publish tile0 ----
  STAGEU(0, 0) STAGEU(1, 0) STAGEU(2, 0) STAGEU(3, 0)
  STAGEU(4, 0) STAGEU(5, 0) STAGEU(6, 0) STAGEU(7, 0)
  STAGEU(0, 1) STAGEU(1, 1)
  asm volatile("s_waitcnt vmcnt(2)" ::: "memory");
  __builtin_amdgcn_sched_barrier(0);
  __builtin_amdgcn_s_barrier();
  LDSA(a0_, 0, 0)
  STAGEU(2, 1) STAGEU(3, 1)
  LDSB(b0_, 0, 0)

  for (int t = 0; t < nt; ++t) {
    const int cp = t & 1, np = (t + 1) & 1;
    // ---- ph0 ----
    LDSB(b1_, 1, cp)
    STAGEU(4, t + 1) STAGEU(5, t + 1)
    __builtin_amdgcn_s_setprio(1);
    MFMA12(0, 0, a0_, b0_)
    __builtin_amdgcn_s_setprio(0);
    // ---- ph1 ----
    LDSA(a1_, 1, cp)
    STAGEU(6, t + 1) STAGEU(7, t + 1)
    __builtin_amdgcn_s_setprio(1);
    MFMA12(0, 1, a0_, b1_)
    __builtin_amdgcn_s_setprio(0);
    // ---- ph2 ----
    asm volatile("s_waitcnt lgkmcnt(0)" ::: "memory");
    asm volatile("s_waitcnt vmcnt(6)" ::: "memory");
    __builtin_amdgcn_sched_barrier(0);
    __builtin_amdgcn_s_barrier();
    LDSA(a0_, 0, np)
    STAGEU(0, t + 2) STAGEU(1, t + 2)
    __builtin_amdgcn_s_setprio(1);
    MFMA12(1, 0, a1_, b0_)
    __builtin_amdgcn_s_setprio(0);
    // ---- ph3 ----
    asm volatile("s_waitcnt vmcnt(2)" ::: "memory");
    __builtin_amdgcn_sched_barrier(0);
    __builtin_amdgcn_s_barrier();
    LDSB(b0_, 0, np)
    STAGEU(2, t + 2) STAGEU(3, t + 2)
    __builtin_amdgcn_s_setprio(1);
    MFMA12(1, 1, a1_, b1_)
    __builtin_amdgcn_s_setprio(0);
  }

  // drain outstanding DMA before epilogue / endpgm
  asm volatile("s_waitcnt vmcnt(0)" ::: "memory");

  float s = gptr[0] / sqrtf(ssptr[0]);
#pragma unroll
  for (int nj = 0; nj < 6; ++nj) {
    int gcol = bn * 384 + wn * 96 + nj * 16 + l15;
    float bv = bias[gcol];
#pragma unroll
    for (int mi = 0; mi < 4; ++mi) {
#pragma unroll
      for (int r = 0; r < 4; ++r) {
        int grow = bm * 128 + wm * 64 + mi * 16 + l4 * 4 + r;
        float v = fmaxf(acc[mi][nj][r] * s + bv, 0.f);
        C[(size_t)grow * N + gcol] = f2bf(v);
      }
    }
  }
#undef STAGEU
#undef LDSA
#undef LDSB
#undef MFMA12
}

// ---------------- bf16 GEMM (m97 structure) for the small GEMM ----------------
__global__ __launch_bounds__(256, 2) void k_gemm_bt(
    const unsigned short* __restrict__ A, const unsigned short* __restrict__ B,
    const float* __restrict__ bias, const float* __restrict__ gptr,
    const float* __restrict__ ssptr, unsigned short* __restrict__ C,
    int M, int N, int K, int nbn) {
  __shared__ __align__(16) unsigned short lA[128 * 64];
  __shared__ __align__(16) unsigned short lB[128 * 64];
  int tid = threadIdx.x;
  int wid = tid >> 6, lane = tid & 63;
  int l15 = lane & 15, l4 = lane >> 4;
  int w0 = wid >> 1, w1 = wid & 1;

  int nwg = gridDim.x;
  int wg = blockIdx.x;
  int cpx = nwg >> 3;
  wg = (wg & 7) * cpx + (wg >> 3);
  int bm = wg / nbn, bn = wg % nbn;

  const unsigned short* Ab = A + (size_t)bm * 128 * K;
  const unsigned short* Bb = B + (size_t)bn * 128 * K;

  f32x4 acc[4][4] = {};

  for (int k0 = 0; k0 < K; k0 += 64) {
    __syncthreads();
#pragma unroll
    for (int i = 0; i < 4; ++i) {
      int ebase = (i * 4 + wid) << 9;
      int eoff = ebase + lane * 8;
      int row = eoff >> 6, col = eoff & 63;
      __builtin_amdgcn_global_load_lds(
          (gas_u32*)(Ab + (size_t)row * K + k0 + col),
          (las_u32*)(lA + ebase), 16, 0, 0);
      __builtin_amdgcn_global_load_lds(
          (gas_u32*)(Bb + (size_t)row * K + k0 + col),
          (las_u32*)(lB + ebase), 16, 0, 0);
    }
    __syncthreads();
#pragma unroll
    for (int ks = 0; ks < 2; ++ks) {
      bf16x8 af[4], bfr[4];
#pragma unroll
      for (int mi = 0; mi < 4; ++mi)
        af[mi] = *(const bf16x8*)(lA + ((w0 * 64 + mi * 16 + l15) * 64 + ks * 32 + l4 * 8));
#pragma unroll
      for (int nj = 0; nj < 4; ++nj)
        bfr[nj] = *(const bf16x8*)(lB + ((w1 * 64 + nj * 16 + l15) * 64 + ks * 32 + l4 * 8));
#pragma unroll
      for (int mi = 0; mi < 4; ++mi)
#pragma unroll
        for (int nj = 0; nj < 4; ++nj)
          acc[mi][nj] =
              __builtin_amdgcn_mfma_f32_16x16x32_bf16(af[mi], bfr[nj], acc[mi][nj], 0, 0, 0);
    }
  }

  float s = gptr[0] / sqrtf(ssptr[0]);
#pragma unroll
  for (int mi = 0; mi < 4; ++mi)
#pragma unroll
    for (int nj = 0; nj < 4; ++nj) {
      int col = bn * 128 + w1 * 64 + nj * 16 + l15;
      float bv = bias[col];
#pragma unroll
      for (int r = 0; r < 4; ++r) {
        int row = bm * 128 + w0 * 64 + mi * 16 + l4 * 4 + r;
        float v = fmaxf(acc[mi][nj][r] * s + bv, 0.f);
        C[(size_t)row * N + col] = f2bf(v);
      }
    }
}

// -------- glimpse (h-paired): out[b,h,v,q] = sum_k hm[h,k]*v_[b,v,k]*q_[b,q,k] + hb[h]
// block = (h2*64 + b), h2 in 0..3, computes heads h2 and h2+4 off ONE V-tile staging.
// 256 blocks = 1/CU even; V DMA traffic halved vs 1-head blocks.
__global__ __launch_bounds__(256, 2) void k_glimpse2(
    const unsigned short* __restrict__ Vh, const unsigned short* __restrict__ Qh,
    const float* __restrict__ hmat, const float* __restrict__ hbias,
    float* __restrict__ out) {
  __shared__ __align__(16) unsigned short lV[128 * 64];
  __shared__ __align__(16) unsigned short lQ[2][32 * 64];
  int tid = threadIdx.x;
  int wid = tid >> 6, lane = tid & 63;
  int l15 = lane & 15, l4 = lane >> 4;

  int id = blockIdx.x;
  int b = id & 63, h2 = id >> 6;  // heads h2, h2+4

  const unsigned short* Vb = Vh + (size_t)b * 128 * 3072;
  const unsigned short* Qb = Qh + (size_t)b * 32 * 3072;
  const float* hr0 = hmat + h2 * 3072;
  const float* hr1 = hmat + (h2 + 4) * 3072;

  f32x4 acc[2][2][2] = {};

  int eoff = tid * 8;
  int qr = eoff >> 6, qc = eoff & 63;

  for (int k0 = 0; k0 < 3072; k0 += 64) {
    __syncthreads();
#pragma unroll
    for (int i = 0; i < 4; ++i) {
      int ebase = (i * 4 + wid) << 9;
      int eo = ebase + lane * 8;
      int row = eo >> 6, col = eo & 63;
      __builtin_amdgcn_global_load_lds(
          (gas_u32*)(Vb + (size_t)row * 3072 + k0 + col),
          (las_u32*)(lV + ebase), 16, 0, 0);
    }
    {
      uint4 qv = *(const uint4*)(Qb + (size_t)qr * 3072 + k0 + qc);
      float e0 = bf2f((unsigned short)(qv.x & 0xffff)), e1 = bf2f((unsigned short)(qv.x >> 16));
      float e2 = bf2f((unsigned short)(qv.y & 0xffff)), e3 = bf2f((unsigned short)(qv.y >> 16));
      float e4 = bf2f((unsigned short)(qv.z & 0xffff)), e5 = bf2f((unsigned short)(qv.z >> 16));
      float e6 = bf2f((unsigned short)(qv.w & 0xffff)), e7 = bf2f((unsigned short)(qv.w >> 16));
      const float* hp0 = hr0 + k0 + qc;
      const float* hp1 = hr1 + k0 + qc;
      float4 p00 = ((const float4*)hp0)[0], p01 = ((const float4*)hp0)[1];
      float4 p10 = ((const float4*)hp1)[0], p11 = ((const float4*)hp1)[1];
      uint4 o0, o1;
      o0.x = f2bf(e0 * p00.x) | ((unsigned)f2bf(e1 * p00.y) << 16);
      o0.y = f2bf(e2 * p00.z) | ((unsigned)f2bf(e3 * p00.w) << 16);
      o0.z = f2bf(e4 * p01.x) | ((unsigned)f2bf(e5 * p01.y) << 16);
      o0.w = f2bf(e6 * p01.z) | ((unsigned)f2bf(e7 * p01.w) << 16);
      o1.x = f2bf(e0 * p10.x) | ((unsigned)f2bf(e1 * p10.y) << 16);
      o1.y = f2bf(e2 * p10.z) | ((unsigned)f2bf(e3 * p10.w) << 16);
      o1.z = f2bf(e4 * p11.x) | ((unsigned)f2bf(e5 * p11.y) << 16);
      o1.w = f2bf(e6 * p11.z) | ((unsigned)f2bf(e7 * p11.w) << 16);
      *(uint4*)(lQ[0] + eoff) = o0;
      *(uint4*)(lQ[1] + eoff) = o1;
    }
    __syncthreads();
#pragma unroll
    for (int ks = 0; ks < 2; ++ks) {
      bf16x8 af[2];
#pragma unroll
      for (int mi = 0; mi < 2; ++mi)
        af[mi] = *(const bf16x8*)(lV + ((wid * 32 + mi * 16 + l15) * 64 + ks * 32 + l4 * 8));
#pragma unroll
      for (int hh = 0; hh < 2; ++hh) {
        bf16x8 bf2[2];
#pragma unroll
        for (int nj = 0; nj < 2; ++nj)
          bf2[nj] = *(const bf16x8*)(lQ[hh] + ((nj * 16 + l15) * 64 + ks * 32 + l4 * 8));
#pragma unroll
        for (int mi = 0; mi < 2; ++mi)
#pragma unroll
          for (int nj = 0; nj < 2; ++nj)
            acc[hh][mi][nj] = __builtin_amdgcn_mfma_f32_16x16x32_bf16(
                af[mi], bf2[nj], acc[hh][mi][nj], 0, 0, 0);
      }
    }
  }

#pragma unroll
  for (int hh = 0; hh < 2; ++hh) {
    int h = h2 + hh * 4;
    float hb = hbias[h];
    float* ob = out + (size_t)(b * 8 + h) * 128 * 32;
#pragma unroll
    for (int mi = 0; mi < 2; ++mi)
#pragma unroll
      for (int nj = 0; nj < 2; ++nj)
#pragma unroll
        for (int r = 0; r < 4; ++r) {
          int row = wid * 32 + mi * 16 + l4 * 4 + r;
          int col = nj * 16 + l15;
          ob[row * 32 + col] = acc[hh][mi][nj][r] + hb;
        }
  }
}

extern "C" void kernel_launch(void* const* d_in, const int* in_sizes, int n_in,
                              void* d_out, int out_size, void* d_ws, size_t ws_size,
                              hipStream_t stream) {
  const float* v = (const float*)d_in[0];
  const float* q = (const float*)d_in[1];
  const float* v_w = (const float*)d_in[2];
  const float* v_g = (const float*)d_in[3];
  const float* v_b = (const float*)d_in[4];
  const float* q_w = (const float*)d_in[5];
  const float* q_g = (const float*)d_in[6];
  const float* q_b = (const float*)d_in[7];
  const float* hmat = (const float*)d_in[8];
  const float* hbias = (const float*)d_in[9];
  float* out = (float*)d_out;

  const size_t n_v = 16777216;   // 64*128*2048
  const size_t n_vw = 6291456;   // 3072*2048
  const size_t n_q = 2097152;    // 64*32*1024
  const size_t n_qw = 3145728;   // 3072*1024
  const size_t n_vh = 25165824;  // 8192*3072
  const size_t n_qh = 6291456;   // 2048*3072

  char* ws = (char*)d_ws;
  float* ss = (float*)ws;
  size_t off = 256;
  unsigned short* v_bf = (unsigned short*)(ws + off);  off += n_v * 2;
  unsigned short* vw_bf = (unsigned short*)(ws + off); off += n_vw * 2;
  unsigned short* q_bf = (unsigned short*)(ws + off);  off += n_q * 2;
  unsigned short* qw_bf = (unsigned short*)(ws + off); off += n_qw * 2;
  unsigned short* v_h = (unsigned short*)(ws + off);   off += n_vh * 2;
  unsigned short* q_h = (unsigned short*)(ws + off);   off += n_qh * 2;

  (void)hipMemsetAsync(ss, 0, 8, stream);
  k_sumsq<<<512, 256, 0, stream>>>(v_w, (int)(n_vw / 4), ss + 0);
  k_sumsq<<<512, 256, 0, stream>>>(q_w, (int)(n_qw / 4), ss + 1);

  k_cvt<<<1024, 256, 0, stream>>>(v, v_bf, (int)(n_v / 8));
  k_cvt<<<1024, 256, 0, stream>>>(v_w, vw_bf, (int)(n_vw / 8));
  k_cvt<<<1024, 256, 0, stream>>>(q, q_bf, (int)(n_q / 8));
  k_cvt<<<1024, 256, 0, stream>>>(q_w, qw_bf, (int)(n_qw / 8));

  // GEMM1: 8192x3072x2048, 128x384 tiles -> 64x8 = 512 blocks = 2/CU (tail-free)
  k_gemm_wn<<<512, 512, 0, stream>>>(v_bf, vw_bf, v_b, v_g, ss + 0, v_h,
                                     8192, 3072, 2048, 8);
  // GEMM2: 2048x3072x1024, 128^2 tiles -> 16x24 = 384 blocks
  k_gemm_bt<<<384, 256, 0, stream>>>(q_bf, qw_bf, q_b, q_g, ss + 1, q_h,
                                     2048, 3072, 1024, 24);

  k_glimpse2<<<256, 256, 0, stream>>>(v_h, q_h, hmat, hbias, out);
}